// Round 2
// baseline (658.104 us; speedup 1.0000x reference)
//
#include <hip/hip_runtime.h>
#include <hip/hip_bf16.h>

// ---------------------------------------------------------------------------
// SingleHeadAttention: b=8, t=2048, e=1024. I/O = float32 (per reference).
//   Q = (q @ Wq^T)/e^0.25 ; K = (k @ Wk^T)/e^0.25 ; V = v @ Wv^T
//   S = Q K^T (causal) ; P = softmax(S) ; O = P V
// Internals in bf16 (MFMA); f32 accumulate; output stored f32.
// Stage 1: proj_kernel  (f32 in -> bf16 Q, K row-major; V^T f-major) in ws
// Stage 2: score_kernel -> S bf16 (lower-triangular tiles only)
// Stage 3: softmax_kernel (in-place S -> P, f32 math)
// Stage 4: out_kernel   -> O = P @ V (NT via V^T), f32 out
// ---------------------------------------------------------------------------

typedef short short8 __attribute__((ext_vector_type(8)));   // 8 x bf16 fragment
typedef float f32x4 __attribute__((ext_vector_type(4)));
typedef int   int4v __attribute__((ext_vector_type(4)));

#define BM 128
#define BN 128
#define BK 32
#define LSTR 40   // LDS row stride (elements): 32 + 8 pad, 16B-aligned rows

static constexpr int B_ = 8;
static constexpr int T_ = 2048;
static constexpr int E_ = 1024;

__device__ __forceinline__ float bf2f(ushort u) {
    union { unsigned int i; float f; } x; x.i = ((unsigned int)u) << 16; return x.f;
}
__device__ __forceinline__ ushort f2bf(float f) {
    union { float f; unsigned int i; } x; x.f = f;
    unsigned int r = x.i + 0x7fffu + ((x.i >> 16) & 1u);   // RNE
    return (ushort)(r >> 16);
}
__device__ __forceinline__ short8 cvt8(f32x4 a, f32x4 b) {
    short8 r;
    r[0] = (short)f2bf(a[0]); r[1] = (short)f2bf(a[1]);
    r[2] = (short)f2bf(a[2]); r[3] = (short)f2bf(a[3]);
    r[4] = (short)f2bf(b[0]); r[5] = (short)f2bf(b[1]);
    r[6] = (short)f2bf(b[2]); r[7] = (short)f2bf(b[3]);
    return r;
}

// ---------------------------------------------------------------------------
// NT GEMM tile core: C[128x128] += A[128xK] * B[128xK]^T. bf16 operands in ws.
__device__ __forceinline__ void gemm_tile_bf16(const ushort* __restrict__ A, int lda,
                                               const ushort* __restrict__ Bm, int ldb,
                                               int ksteps, f32x4 (&acc)[4][4],
                                               ushort* As, ushort* Bs)
{
    const int tid  = threadIdx.x;
    const int lane = tid & 63;
    const int wave = tid >> 6;
    const int wr = (wave >> 1) * 64;
    const int wc = (wave & 1) * 64;

    const int r0 = tid >> 2,         o0 = (tid & 3) * 8;
    const int r1 = (tid + 256) >> 2;

    const int frow = lane & 15;
    const int fk   = (lane >> 4) * 8;

    for (int ks = 0; ks < ksteps; ++ks) {
        const int k0 = ks * BK;
        int4v a0 = *(const int4v*)(A + (size_t)r0 * lda + k0 + o0);
        int4v a1 = *(const int4v*)(A + (size_t)r1 * lda + k0 + o0);
        int4v b0 = *(const int4v*)(Bm + (size_t)r0 * ldb + k0 + o0);
        int4v b1 = *(const int4v*)(Bm + (size_t)r1 * ldb + k0 + o0);
        __syncthreads();   // previous iter's LDS reads complete
        *(int4v*)(As + r0 * LSTR + o0) = a0;
        *(int4v*)(As + r1 * LSTR + o0) = a1;
        *(int4v*)(Bs + r0 * LSTR + o0) = b0;
        *(int4v*)(Bs + r1 * LSTR + o0) = b1;
        __syncthreads();

        short8 af[4], bf[4];
#pragma unroll
        for (int i = 0; i < 4; ++i)
            af[i] = *(const short8*)(As + (wr + i * 16 + frow) * LSTR + fk);
#pragma unroll
        for (int i = 0; i < 4; ++i)
            bf[i] = *(const short8*)(Bs + (wc + i * 16 + frow) * LSTR + fk);
#pragma unroll
        for (int mi = 0; mi < 4; ++mi)
#pragma unroll
            for (int ni = 0; ni < 4; ++ni)
                acc[mi][ni] = __builtin_amdgcn_mfma_f32_16x16x32_bf16(
                    af[mi], bf[ni], acc[mi][ni], 0, 0, 0);
    }
}

// Same core but operands are f32 in global; convert to bf16 while staging.
__device__ __forceinline__ void gemm_tile_f32(const float* __restrict__ A, int lda,
                                              const float* __restrict__ Bm, int ldb,
                                              int ksteps, f32x4 (&acc)[4][4],
                                              ushort* As, ushort* Bs)
{
    const int tid  = threadIdx.x;
    const int lane = tid & 63;
    const int wave = tid >> 6;
    const int wr = (wave >> 1) * 64;
    const int wc = (wave & 1) * 64;

    const int r0 = tid >> 2,         o0 = (tid & 3) * 8;
    const int r1 = (tid + 256) >> 2;

    const int frow = lane & 15;
    const int fk   = (lane >> 4) * 8;

    for (int ks = 0; ks < ksteps; ++ks) {
        const int k0 = ks * BK;
        const float* pa0 = A + (size_t)r0 * lda + k0 + o0;
        const float* pa1 = A + (size_t)r1 * lda + k0 + o0;
        const float* pb0 = Bm + (size_t)r0 * ldb + k0 + o0;
        const float* pb1 = Bm + (size_t)r1 * ldb + k0 + o0;
        f32x4 a00 = *(const f32x4*)(pa0),     a01 = *(const f32x4*)(pa0 + 4);
        f32x4 a10 = *(const f32x4*)(pa1),     a11 = *(const f32x4*)(pa1 + 4);
        f32x4 b00 = *(const f32x4*)(pb0),     b01 = *(const f32x4*)(pb0 + 4);
        f32x4 b10 = *(const f32x4*)(pb1),     b11 = *(const f32x4*)(pb1 + 4);
        __syncthreads();
        *(short8*)(As + r0 * LSTR + o0) = cvt8(a00, a01);
        *(short8*)(As + r1 * LSTR + o0) = cvt8(a10, a11);
        *(short8*)(Bs + r0 * LSTR + o0) = cvt8(b00, b01);
        *(short8*)(Bs + r1 * LSTR + o0) = cvt8(b10, b11);
        __syncthreads();

        short8 af[4], bf[4];
#pragma unroll
        for (int i = 0; i < 4; ++i)
            af[i] = *(const short8*)(As + (wr + i * 16 + frow) * LSTR + fk);
#pragma unroll
        for (int i = 0; i < 4; ++i)
            bf[i] = *(const short8*)(Bs + (wc + i * 16 + frow) * LSTR + fk);
#pragma unroll
        for (int mi = 0; mi < 4; ++mi)
#pragma unroll
            for (int ni = 0; ni < 4; ++ni)
                acc[mi][ni] = __builtin_amdgcn_mfma_f32_16x16x32_bf16(
                    af[mi], bf[ni], acc[mi][ni], 0, 0, 0);
    }
}

// ---------------------------------------------------------------------------
// Stage 1: projections. grid (M/128=128, E/128=8, 3). z: 0=Q,1=K,2=V^T
__global__ __launch_bounds__(256, 2)
void proj_kernel(const float* __restrict__ q, const float* __restrict__ k,
                 const float* __restrict__ v,
                 const float* __restrict__ Wq, const float* __restrict__ Wk,
                 const float* __restrict__ Wv,
                 ushort* __restrict__ Q, ushort* __restrict__ Kp,
                 ushort* __restrict__ Vt)
{
    __shared__ ushort As[BM * LSTR];
    __shared__ ushort Bs[BN * LSTR];
    const int z = blockIdx.z;
    const float* A = (z == 0 ? q : (z == 1 ? k : v)) + (size_t)blockIdx.x * 128 * E_;
    const float* W = (z == 0 ? Wq : (z == 1 ? Wk : Wv)) + (size_t)blockIdx.y * 128 * E_;

    f32x4 acc[4][4];
#pragma unroll
    for (int i = 0; i < 4; ++i)
#pragma unroll
        for (int j = 0; j < 4; ++j) acc[i][j] = (f32x4){0.f, 0.f, 0.f, 0.f};

    gemm_tile_f32(A, E_, W, E_, E_ / BK, acc, As, Bs);

    const int lane = threadIdx.x & 63;
    const int wave = threadIdx.x >> 6;
    const int wr = (wave >> 1) * 64, wc = (wave & 1) * 64;
    const float scale = (z == 2) ? 1.0f : 0.17677669529663687f;  // 1/e^(1/4)

    if (z < 2) {
        ushort* D = (z == 0 ? Q : Kp);
#pragma unroll
        for (int mi = 0; mi < 4; ++mi)
#pragma unroll
            for (int r = 0; r < 4; ++r) {
                const int row = blockIdx.x * 128 + wr + mi * 16 + (lane >> 4) * 4 + r;
#pragma unroll
                for (int ni = 0; ni < 4; ++ni) {
                    const int col = blockIdx.y * 128 + wc + ni * 16 + (lane & 15);
                    D[(size_t)row * E_ + col] = f2bf(acc[mi][ni][r] * scale);
                }
            }
    } else {
        // V^T layout: Vt[b][f][t_local], f-major
#pragma unroll
        for (int mi = 0; mi < 4; ++mi)
#pragma unroll
            for (int r = 0; r < 4; ++r) {
                const int rowg = blockIdx.x * 128 + wr + mi * 16 + (lane >> 4) * 4 + r;
                const int bb = rowg >> 11;          // /2048
                const int tl = rowg & 2047;
#pragma unroll
                for (int ni = 0; ni < 4; ++ni) {
                    const int col = blockIdx.y * 128 + wc + ni * 16 + (lane & 15);
                    Vt[(size_t)bb * E_ * T_ + (size_t)col * T_ + tl] = f2bf(acc[mi][ni][r]);
                }
            }
    }
}

// ---------------------------------------------------------------------------
// Stage 2: S = Q K^T with causal mask. grid (16,16,8); skip tiles above diag.
__global__ __launch_bounds__(256, 2)
void score_kernel(const ushort* __restrict__ Q, const ushort* __restrict__ K,
                  ushort* __restrict__ S)
{
    const int bc = blockIdx.x, br = blockIdx.y, b = blockIdx.z;
    if (bc > br) return;
    __shared__ ushort As[BM * LSTR];
    __shared__ ushort Bs[BN * LSTR];
    const ushort* A = Q + ((size_t)b * T_ + br * 128) * E_;
    const ushort* Bm = K + ((size_t)b * T_ + bc * 128) * E_;

    f32x4 acc[4][4];
#pragma unroll
    for (int i = 0; i < 4; ++i)
#pragma unroll
        for (int j = 0; j < 4; ++j) acc[i][j] = (f32x4){0.f, 0.f, 0.f, 0.f};

    gemm_tile_bf16(A, E_, Bm, E_, E_ / BK, acc, As, Bs);

    const int lane = threadIdx.x & 63;
    const int wave = threadIdx.x >> 6;
    const int wr = (wave >> 1) * 64, wc = (wave & 1) * 64;
    ushort* Sb = S + (size_t)b * T_ * T_;
#pragma unroll
    for (int mi = 0; mi < 4; ++mi)
#pragma unroll
        for (int r = 0; r < 4; ++r) {
            const int row = br * 128 + wr + mi * 16 + (lane >> 4) * 4 + r;
#pragma unroll
            for (int ni = 0; ni < 4; ++ni) {
                const int col = bc * 128 + wc + ni * 16 + (lane & 15);
                float val = acc[mi][ni][r];
                if (col > row) val = -1e30f;
                Sb[(size_t)row * T_ + col] = f2bf(val);
            }
        }
}

// ---------------------------------------------------------------------------
// Stage 3: row softmax in place. grid 16384 blocks x 256 threads.
__global__ __launch_bounds__(256)
void softmax_kernel(ushort* __restrict__ S)
{
    const int gr = blockIdx.x;
    const int b = gr >> 11, i = gr & 2047;
    ushort* row = S + (size_t)b * T_ * T_ + (size_t)i * T_;
    const int Lpad = ((i >> 7) + 1) * 128;   // 128-aligned causal span
    const int tid = threadIdx.x;
    const int lane = tid & 63, wave = tid >> 6;
    __shared__ float red[4];

    float xv[8];
    int n = 0;
    for (int j = tid; j < Lpad; j += 256) xv[n++] = bf2f(row[j]);

    float m = -1e30f;
    for (int t = 0; t < n; ++t) m = fmaxf(m, xv[t]);
#pragma unroll
    for (int o = 32; o; o >>= 1) m = fmaxf(m, __shfl_xor(m, o, 64));
    if (lane == 0) red[wave] = m;
    __syncthreads();
    m = fmaxf(fmaxf(red[0], red[1]), fmaxf(red[2], red[3]));
    __syncthreads();

    float s = 0.f;
    for (int t = 0; t < n; ++t) { xv[t] = __expf(xv[t] - m); s += xv[t]; }
#pragma unroll
    for (int o = 32; o; o >>= 1) s += __shfl_xor(s, o, 64);
    if (lane == 0) red[wave] = s;
    __syncthreads();
    s = red[0] + red[1] + red[2] + red[3];
    const float inv = 1.0f / s;

    int t = 0;
    for (int j = tid; j < Lpad; j += 256, ++t) row[j] = f2bf(xv[t] * inv);
}

// ---------------------------------------------------------------------------
// Stage 4: O = P @ V via V^T (NT). grid (E/128=8, T/128=16, 8). f32 output.
__global__ __launch_bounds__(256, 2)
void out_kernel(const ushort* __restrict__ P, const ushort* __restrict__ Vt,
                float* __restrict__ O)
{
    const int bc = blockIdx.x, br = blockIdx.y, b = blockIdx.z;
    __shared__ ushort As[BM * LSTR];
    __shared__ ushort Bs[BN * LSTR];
    const ushort* A  = P + (size_t)b * T_ * T_ + (size_t)(br * 128) * T_;
    const ushort* Bm = Vt + (size_t)b * E_ * T_ + (size_t)(bc * 128) * T_;
    const int ksteps = (br + 1) * (128 / BK);   // causal K-limit

    f32x4 acc[4][4];
#pragma unroll
    for (int i = 0; i < 4; ++i)
#pragma unroll
        for (int j = 0; j < 4; ++j) acc[i][j] = (f32x4){0.f, 0.f, 0.f, 0.f};

    gemm_tile_bf16(A, T_, Bm, T_, ksteps, acc, As, Bs);

    const int lane = threadIdx.x & 63;
    const int wave = threadIdx.x >> 6;
    const int wr = (wave >> 1) * 64, wc = (wave & 1) * 64;
    float* Ob = O + (size_t)b * T_ * E_;
#pragma unroll
    for (int mi = 0; mi < 4; ++mi)
#pragma unroll
        for (int r = 0; r < 4; ++r) {
            const int row = br * 128 + wr + mi * 16 + (lane >> 4) * 4 + r;
#pragma unroll
            for (int ni = 0; ni < 4; ++ni) {
                const int col = bc * 128 + wc + ni * 16 + (lane & 15);
                Ob[(size_t)row * E_ + col] = acc[mi][ni][r];
            }
        }
}

// ---------------------------------------------------------------------------
extern "C" void kernel_launch(void* const* d_in, const int* in_sizes, int n_in,
                              void* d_out, int out_size, void* d_ws, size_t ws_size,
                              hipStream_t stream)
{
    const float* q  = (const float*)d_in[0];
    const float* k  = (const float*)d_in[1];
    const float* v  = (const float*)d_in[2];
    const float* Wq = (const float*)d_in[3];
    const float* Wk = (const float*)d_in[4];
    const float* Wv = (const float*)d_in[5];
    float* out = (float*)d_out;

    const size_t nQKV = (size_t)B_ * T_ * E_;      // 16,777,216
    ushort* Q  = (ushort*)d_ws;
    ushort* K  = Q + nQKV;
    ushort* Vt = K + nQKV;
    ushort* S  = Vt + nQKV;                        // 8*2048*2048 elements (67 MB)

    proj_kernel<<<dim3(B_ * T_ / 128, E_ / 128, 3), 256, 0, stream>>>(
        q, k, v, Wq, Wk, Wv, Q, K, Vt);
    score_kernel<<<dim3(T_ / 128, T_ / 128, B_), 256, 0, stream>>>(Q, K, S);
    softmax_kernel<<<dim3(B_ * T_), 256, 0, stream>>>(S);
    out_kernel<<<dim3(E_ / 128, T_ / 128, B_), 256, 0, stream>>>(S, Vt, out);
}

// Round 3
// 538.839 us; speedup vs baseline: 1.2213x; 1.2213x over previous
//
#include <hip/hip_runtime.h>
#include <hip/hip_bf16.h>

// ---------------------------------------------------------------------------
// SingleHeadAttention: b=8, t=2048, e=1024. I/O = float32.
//   Q = (q @ Wq^T)/e^0.25 ; K = (k @ Wk^T)/e^0.25 ; V = v @ Wv^T
//   S = Q K^T (causal) ; P = softmax(S) ; O = P V
// bf16 MFMA internals, f32 accumulate, f32 output.
//
// ws layout (160 MiB, same footprint as the round-2 PASS):
//   [Q 33.5MB][K 33.5MB][Vt 33.5MB][S 67MB]
// The S region is dead until score_kernel, so the f32->bf16 converted
// weights (6 MB) and a single shared X buffer (33.5 MB) alias into it:
//   Wb = S+0, Xb = S+3M ushorts. Stream order serializes the reuse.
//
// GEMM core: m97-style async staging — __builtin_amdgcn_global_load_lds
// width=16, unpadded 128x32 LDS tiles, 2-barrier K-loop.
// ---------------------------------------------------------------------------

typedef short short8 __attribute__((ext_vector_type(8)));   // 8 x bf16
typedef float f32x4 __attribute__((ext_vector_type(4)));
typedef int   int4v __attribute__((ext_vector_type(4)));

#define BK 32

static constexpr int B_ = 8;
static constexpr int T_ = 2048;
static constexpr int E_ = 1024;

__device__ __forceinline__ float bf2f(ushort u) {
    union { unsigned int i; float f; } x; x.i = ((unsigned int)u) << 16; return x.f;
}
__device__ __forceinline__ ushort f2bf(float f) {
    union { float f; unsigned int i; } x; x.f = f;
    unsigned int r = x.i + 0x7fffu + ((x.i >> 16) & 1u);   // RNE
    return (ushort)(r >> 16);
}
__device__ __forceinline__ short8 cvt8(f32x4 a, f32x4 b) {
    short8 r;
    r[0] = (short)f2bf(a[0]); r[1] = (short)f2bf(a[1]);
    r[2] = (short)f2bf(a[2]); r[3] = (short)f2bf(a[3]);
    r[4] = (short)f2bf(b[0]); r[5] = (short)f2bf(b[1]);
    r[6] = (short)f2bf(b[2]); r[7] = (short)f2bf(b[3]);
    return r;
}

// async 16B global -> LDS. lds ptr must be wave-uniform; lane i lands at +16*i.
__device__ __forceinline__ void async16(const ushort* g, ushort* l) {
    __builtin_amdgcn_global_load_lds(
        (const __attribute__((address_space(1))) unsigned int*)g,
        (__attribute__((address_space(3))) unsigned int*)l,
        16, 0, 0);
}

// ---------------------------------------------------------------------------
// NT GEMM tile: C[128x128] += A[128xK] * B[128xK]^T, bf16, K contiguous.
// LDS tiles 128x32 unpadded (global_load_lds requires contiguous lane order).
__device__ __forceinline__ void gemm_tile(const ushort* __restrict__ A, int lda,
                                          const ushort* __restrict__ Bm, int ldb,
                                          int ksteps, f32x4 (&acc)[4][4],
                                          ushort* As, ushort* Bs)
{
    const int tid  = threadIdx.x;
    const int lane = tid & 63;
    const int wave = tid >> 6;
    const int wr = (wave >> 1) * 64;
    const int wc = (wave & 1) * 64;

    // staging: 8 chunks of 1024B per operand tile; wave w issues chunks 2w,2w+1
    const int c0 = wave * 2, c1 = wave * 2 + 1;
    const int lrow0 = c0 * 16 + (lane >> 2);       // global row for this lane
    const int lrow1 = c1 * 16 + (lane >> 2);
    const int lcol  = (lane & 3) * 8;              // col offset (elements)
    ushort* ldsA0 = As + c0 * 512;                 // wave-uniform LDS bases
    ushort* ldsA1 = As + c1 * 512;
    ushort* ldsB0 = Bs + c0 * 512;
    ushort* ldsB1 = Bs + c1 * 512;

    const int frow = lane & 15;
    const int fk   = (lane >> 4) * 8;

    for (int ks = 0; ks < ksteps; ++ks) {
        const int k0 = ks * BK;
        __syncthreads();   // prior iter's ds_reads complete before overwrite
        async16(A  + (size_t)lrow0 * lda + k0 + lcol, ldsA0);
        async16(A  + (size_t)lrow1 * lda + k0 + lcol, ldsA1);
        async16(Bm + (size_t)lrow0 * ldb + k0 + lcol, ldsB0);
        async16(Bm + (size_t)lrow1 * ldb + k0 + lcol, ldsB1);
        __syncthreads();   // compiler drains vmcnt(0) before barrier

        short8 af[4], bf[4];
#pragma unroll
        for (int i = 0; i < 4; ++i)
            af[i] = *(const short8*)(As + (wr + i * 16 + frow) * BK + fk);
#pragma unroll
        for (int i = 0; i < 4; ++i)
            bf[i] = *(const short8*)(Bs + (wc + i * 16 + frow) * BK + fk);
#pragma unroll
        for (int mi = 0; mi < 4; ++mi)
#pragma unroll
            for (int ni = 0; ni < 4; ++ni)
                acc[mi][ni] = __builtin_amdgcn_mfma_f32_16x16x32_bf16(
                    af[mi], bf[ni], acc[mi][ni], 0, 0, 0);
    }
}

// ---------------------------------------------------------------------------
// f32 -> bf16 converter. grid.x covers n/2048 blocks; 8 elems/thread.
__global__ __launch_bounds__(256)
void cvt_kernel(const float* __restrict__ s, ushort* __restrict__ d, int n)
{
    const int idx = (blockIdx.x * 256 + threadIdx.x) * 8;
    if (idx < n) {
        f32x4 a = *(const f32x4*)(s + idx);
        f32x4 b = *(const f32x4*)(s + idx + 4);
        *(short8*)(d + idx) = cvt8(a, b);
    }
}

// Converts the three 1024x1024 weight matrices in one launch (grid.y = 3).
__global__ __launch_bounds__(256)
void cvtW_kernel(const float* __restrict__ w0, const float* __restrict__ w1,
                 const float* __restrict__ w2, ushort* __restrict__ d)
{
    const float* s = blockIdx.y == 0 ? w0 : (blockIdx.y == 1 ? w1 : w2);
    ushort* dd = d + (size_t)blockIdx.y * E_ * E_;
    const int idx = (blockIdx.x * 256 + threadIdx.x) * 8;
    f32x4 a = *(const f32x4*)(s + idx);
    f32x4 b = *(const f32x4*)(s + idx + 4);
    *(short8*)(dd + idx) = cvt8(a, b);
}

// ---------------------------------------------------------------------------
// Stage 1: one projection. grid (M/128=128, E/128=8).
// mode 0: D = (X W^T)*scale row-major.  mode 1: D = X W^T transposed (Vt).
__global__ __launch_bounds__(256, 4)
void proj_kernel(const ushort* __restrict__ X, const ushort* __restrict__ W,
                 ushort* __restrict__ D, int mode, float scale)
{
    __shared__ ushort As[128 * BK];
    __shared__ ushort Bs[128 * BK];
    const ushort* A = X + (size_t)blockIdx.x * 128 * E_;
    const ushort* B = W + (size_t)blockIdx.y * 128 * E_;

    f32x4 acc[4][4];
#pragma unroll
    for (int i = 0; i < 4; ++i)
#pragma unroll
        for (int j = 0; j < 4; ++j) acc[i][j] = (f32x4){0.f, 0.f, 0.f, 0.f};

    gemm_tile(A, E_, B, E_, E_ / BK, acc, As, Bs);

    const int lane = threadIdx.x & 63;
    const int wave = threadIdx.x >> 6;
    const int wr = (wave >> 1) * 64, wc = (wave & 1) * 64;

    if (mode == 0) {
#pragma unroll
        for (int mi = 0; mi < 4; ++mi)
#pragma unroll
            for (int r = 0; r < 4; ++r) {
                const int row = blockIdx.x * 128 + wr + mi * 16 + (lane >> 4) * 4 + r;
#pragma unroll
                for (int ni = 0; ni < 4; ++ni) {
                    const int col = blockIdx.y * 128 + wc + ni * 16 + (lane & 15);
                    D[(size_t)row * E_ + col] = f2bf(acc[mi][ni][r] * scale);
                }
            }
    } else {
        // Vt layout: D[b][f][t_local]
#pragma unroll
        for (int mi = 0; mi < 4; ++mi)
#pragma unroll
            for (int r = 0; r < 4; ++r) {
                const int rowg = blockIdx.x * 128 + wr + mi * 16 + (lane >> 4) * 4 + r;
                const int bb = rowg >> 11;
                const int tl = rowg & 2047;
#pragma unroll
                for (int ni = 0; ni < 4; ++ni) {
                    const int col = blockIdx.y * 128 + wc + ni * 16 + (lane & 15);
                    D[(size_t)bb * E_ * T_ + (size_t)col * T_ + tl] = f2bf(acc[mi][ni][r]);
                }
            }
    }
}

// ---------------------------------------------------------------------------
// Stage 2: S = Q K^T causal. grid (16,16,8); tiles above diagonal skipped.
__global__ __launch_bounds__(256, 4)
void score_kernel(const ushort* __restrict__ Q, const ushort* __restrict__ K,
                  ushort* __restrict__ S)
{
    const int bc = blockIdx.x, br = blockIdx.y, b = blockIdx.z;
    if (bc > br) return;
    __shared__ ushort As[128 * BK];
    __shared__ ushort Bs[128 * BK];
    const ushort* A = Q + ((size_t)b * T_ + br * 128) * E_;
    const ushort* B = K + ((size_t)b * T_ + bc * 128) * E_;

    f32x4 acc[4][4];
#pragma unroll
    for (int i = 0; i < 4; ++i)
#pragma unroll
        for (int j = 0; j < 4; ++j) acc[i][j] = (f32x4){0.f, 0.f, 0.f, 0.f};

    gemm_tile(A, E_, B, E_, E_ / BK, acc, As, Bs);

    const int lane = threadIdx.x & 63;
    const int wave = threadIdx.x >> 6;
    const int wr = (wave >> 1) * 64, wc = (wave & 1) * 64;
    ushort* Sb = S + (size_t)b * T_ * T_;
#pragma unroll
    for (int mi = 0; mi < 4; ++mi)
#pragma unroll
        for (int r = 0; r < 4; ++r) {
            const int row = br * 128 + wr + mi * 16 + (lane >> 4) * 4 + r;
#pragma unroll
            for (int ni = 0; ni < 4; ++ni) {
                const int col = bc * 128 + wc + ni * 16 + (lane & 15);
                float val = acc[mi][ni][r];
                if (col > row) val = -1e30f;
                Sb[(size_t)row * T_ + col] = f2bf(val);
            }
        }
}

// ---------------------------------------------------------------------------
// Stage 3: row softmax in place, 16B vector I/O. One block per row.
__global__ __launch_bounds__(256)
void softmax_kernel(ushort* __restrict__ S)
{
    const int gr = blockIdx.x;
    const int b = gr >> 11, i = gr & 2047;
    ushort* row = S + (size_t)b * T_ * T_ + (size_t)i * T_;
    const int Lpad = ((i >> 7) + 1) * 128;   // 128-aligned causal span
    const int tid = threadIdx.x;
    const int lane = tid & 63, wave = tid >> 6;
    __shared__ float red[4];

    const int j0 = tid * 8;                  // 256*8 = 2048 covers max row
    const bool act = j0 < Lpad;
    float xv[8];
    if (act) {
        int4v dv = *(const int4v*)(row + j0);
        const ushort* u = (const ushort*)&dv;
#pragma unroll
        for (int t = 0; t < 8; ++t) xv[t] = bf2f(u[t]);
    }

    float m = -1e30f;
    if (act)
#pragma unroll
        for (int t = 0; t < 8; ++t) m = fmaxf(m, xv[t]);
#pragma unroll
    for (int o = 32; o; o >>= 1) m = fmaxf(m, __shfl_xor(m, o, 64));
    if (lane == 0) red[wave] = m;
    __syncthreads();
    m = fmaxf(fmaxf(red[0], red[1]), fmaxf(red[2], red[3]));
    __syncthreads();

    float s = 0.f;
    if (act)
#pragma unroll
        for (int t = 0; t < 8; ++t) { xv[t] = __expf(xv[t] - m); s += xv[t]; }
#pragma unroll
    for (int o = 32; o; o >>= 1) s += __shfl_xor(s, o, 64);
    if (lane == 0) red[wave] = s;
    __syncthreads();
    s = red[0] + red[1] + red[2] + red[3];
    const float inv = 1.0f / s;

    if (act) {
        int4v dv;
        ushort* u = (ushort*)&dv;
#pragma unroll
        for (int t = 0; t < 8; ++t) u[t] = f2bf(xv[t] * inv);
        *(int4v*)(row + j0) = dv;
    }
}

// ---------------------------------------------------------------------------
// Stage 4: O = P @ V via V^T (NT). grid (8,16,8). f32 output.
__global__ __launch_bounds__(256, 4)
void out_kernel(const ushort* __restrict__ P, const ushort* __restrict__ Vt,
                float* __restrict__ O)
{
    const int bc = blockIdx.x, br = blockIdx.y, b = blockIdx.z;
    __shared__ ushort As[128 * BK];
    __shared__ ushort Bs[128 * BK];
    const ushort* A = P  + (size_t)b * T_ * T_ + (size_t)(br * 128) * T_;
    const ushort* B = Vt + (size_t)b * E_ * T_ + (size_t)(bc * 128) * T_;
    const int ksteps = (br + 1) * (128 / BK);   // causal K-limit

    f32x4 acc[4][4];
#pragma unroll
    for (int i = 0; i < 4; ++i)
#pragma unroll
        for (int j = 0; j < 4; ++j) acc[i][j] = (f32x4){0.f, 0.f, 0.f, 0.f};

    gemm_tile(A, T_, B, T_, ksteps, acc, As, Bs);

    const int lane = threadIdx.x & 63;
    const int wave = threadIdx.x >> 6;
    const int wr = (wave >> 1) * 64, wc = (wave & 1) * 64;
    float* Ob = O + (size_t)b * T_ * E_;
#pragma unroll
    for (int mi = 0; mi < 4; ++mi)
#pragma unroll
        for (int r = 0; r < 4; ++r) {
            const int row = br * 128 + wr + mi * 16 + (lane >> 4) * 4 + r;
#pragma unroll
            for (int ni = 0; ni < 4; ++ni) {
                const int col = bc * 128 + wc + ni * 16 + (lane & 15);
                Ob[(size_t)row * E_ + col] = acc[mi][ni][r];
            }
        }
}

// ---------------------------------------------------------------------------
extern "C" void kernel_launch(void* const* d_in, const int* in_sizes, int n_in,
                              void* d_out, int out_size, void* d_ws, size_t ws_size,
                              hipStream_t stream)
{
    const float* q  = (const float*)d_in[0];
    const float* k  = (const float*)d_in[1];
    const float* v  = (const float*)d_in[2];
    const float* Wq = (const float*)d_in[3];
    const float* Wk = (const float*)d_in[4];
    const float* Wv = (const float*)d_in[5];
    float* out = (float*)d_out;

    const size_t nQKV = (size_t)B_ * T_ * E_;      // 16,777,216 elems
    const size_t nW   = (size_t)E_ * E_;           // 1,048,576 elems
    ushort* Q  = (ushort*)d_ws;
    ushort* K  = Q + nQKV;
    ushort* Vt = K + nQKV;
    ushort* S  = Vt + nQKV;                        // 33.55M elems (67 MB)
    // aliases inside the (not-yet-live) S region:
    ushort* Wb = S;                                // 3 x 1M   (6 MB)
    ushort* Xb = S + 3 * nW;                       // 16.77M   (33.5 MB)

    const float qs = 0.17677669529663687f;         // 1/e^(1/4)

    cvtW_kernel<<<dim3(nW / 2048, 3), 256, 0, stream>>>(Wq, Wk, Wv, Wb);

    cvt_kernel<<<dim3(nQKV / 2048), 256, 0, stream>>>(q, Xb, (int)nQKV);
    proj_kernel<<<dim3(128, 8), 256, 0, stream>>>(Xb, Wb,          Q,  0, qs);
    cvt_kernel<<<dim3(nQKV / 2048), 256, 0, stream>>>(k, Xb, (int)nQKV);
    proj_kernel<<<dim3(128, 8), 256, 0, stream>>>(Xb, Wb + nW,     K,  0, qs);
    cvt_kernel<<<dim3(nQKV / 2048), 256, 0, stream>>>(v, Xb, (int)nQKV);
    proj_kernel<<<dim3(128, 8), 256, 0, stream>>>(Xb, Wb + 2 * nW, Vt, 1, 1.0f);

    score_kernel<<<dim3(T_ / 128, T_ / 128, B_), 256, 0, stream>>>(Q, K, S);
    softmax_kernel<<<dim3(B_ * T_), 256, 0, stream>>>(S);
    out_kernel<<<dim3(E_ / 128, T_ / 128, B_), 256, 0, stream>>>(S, Vt, out);
}

// Round 4
// 522.587 us; speedup vs baseline: 1.2593x; 1.0311x over previous
//
#include <hip/hip_runtime.h>
#include <hip/hip_bf16.h>

// ---------------------------------------------------------------------------
// SingleHeadAttention: b=8, t=2048, e=1024. I/O = float32.
//   Q = (q @ Wq^T)/e^0.25 ; K = (k @ Wk^T)/e^0.25 ; V = v @ Wv^T
//   S = Q K^T (causal) ; P = softmax(S) ; O = P V
// bf16 MFMA internals, f32 accumulate, f32 output.
//
// Round-4 structure:
//  - proj reads f32 inputs DIRECTLY (global_load_lds -> f32 LDS tile,
//    f32->bf16 at fragment read). No cvt pre-passes, one merged dispatch
//    (grid.z = 3 -> 3072 blocks, ~12/CU for latency hiding). BK=32.
//  - score/out use BK=64 (halves the per-K-step vmcnt(0) barrier drains,
//    32 MFMA per barrier). score grid = compact lower triangle (136 tiles).
//  - ws: [Q][K][Vt][S]; bf16 weights alias the dead S region during proj.
// ---------------------------------------------------------------------------

typedef short short8 __attribute__((ext_vector_type(8)));   // 8 x bf16
typedef float f32x4 __attribute__((ext_vector_type(4)));
typedef int   int4v __attribute__((ext_vector_type(4)));

static constexpr int B_ = 8;
static constexpr int T_ = 2048;
static constexpr int E_ = 1024;

__device__ __forceinline__ float bf2f(ushort u) {
    union { unsigned int i; float f; } x; x.i = ((unsigned int)u) << 16; return x.f;
}
__device__ __forceinline__ ushort f2bf(float f) {
    union { float f; unsigned int i; } x; x.f = f;
    unsigned int r = x.i + 0x7fffu + ((x.i >> 16) & 1u);   // RNE
    return (ushort)(r >> 16);
}
__device__ __forceinline__ short8 cvt8(f32x4 a, f32x4 b) {
    short8 r;
    r[0] = (short)f2bf(a[0]); r[1] = (short)f2bf(a[1]);
    r[2] = (short)f2bf(a[2]); r[3] = (short)f2bf(a[3]);
    r[4] = (short)f2bf(b[0]); r[5] = (short)f2bf(b[1]);
    r[6] = (short)f2bf(b[2]); r[7] = (short)f2bf(b[3]);
    return r;
}

// async 16B global -> LDS; lds base wave-uniform, lane i lands at +16*i.
__device__ __forceinline__ void async16(const ushort* g, ushort* l) {
    __builtin_amdgcn_global_load_lds(
        (const __attribute__((address_space(1))) unsigned int*)g,
        (__attribute__((address_space(3))) unsigned int*)l, 16, 0, 0);
}
__device__ __forceinline__ void async16f(const float* g, float* l) {
    __builtin_amdgcn_global_load_lds(
        (const __attribute__((address_space(1))) unsigned int*)g,
        (__attribute__((address_space(3))) unsigned int*)l, 16, 0, 0);
}

// ---------------------------------------------------------------------------
// BK=64 NT GEMM tile: C[128x128] += A[128xK] * B[128xK]^T, bf16, K contig.
// LDS 128x64 per operand (16 KB); 1KB chunk = 8 rows of 128B.
__device__ __forceinline__ void gemm_tile64(const ushort* __restrict__ A, int lda,
                                            const ushort* __restrict__ Bm, int ldb,
                                            int ksteps, f32x4 (&acc)[4][4],
                                            ushort* As, ushort* Bs)
{
    const int tid = threadIdx.x, lane = tid & 63, wave = tid >> 6;
    const int wr = (wave >> 1) * 64, wc = (wave & 1) * 64;
    const int srow = lane >> 3;            // row within 8-row chunk
    const int scol = (lane & 7) * 8;       // col (elements)
    const int frow = lane & 15, fk = (lane >> 4) * 8;

    for (int ks = 0; ks < ksteps; ++ks) {
        const int k0 = ks * 64;
        __syncthreads();   // prior iter's ds_reads complete before overwrite
#pragma unroll
        for (int j = 0; j < 4; ++j) {
            const int c = wave * 4 + j;            // 16 chunks per operand
            const int grow = c * 8 + srow;
            async16(A  + (size_t)grow * lda + k0 + scol, As + c * 512);
            async16(Bm + (size_t)grow * ldb + k0 + scol, Bs + c * 512);
        }
        __syncthreads();   // drains vmcnt(0)

        short8 af[4][2], bf[4][2];
#pragma unroll
        for (int i = 0; i < 4; ++i)
#pragma unroll
            for (int kk = 0; kk < 2; ++kk) {
                af[i][kk] = *(const short8*)(As + (wr + i * 16 + frow) * 64 + kk * 32 + fk);
                bf[i][kk] = *(const short8*)(Bs + (wc + i * 16 + frow) * 64 + kk * 32 + fk);
            }
#pragma unroll
        for (int kk = 0; kk < 2; ++kk)
#pragma unroll
            for (int mi = 0; mi < 4; ++mi)
#pragma unroll
                for (int ni = 0; ni < 4; ++ni)
                    acc[mi][ni] = __builtin_amdgcn_mfma_f32_16x16x32_bf16(
                        af[mi][kk], bf[ni][kk], acc[mi][ni], 0, 0, 0);
    }
}

// ---------------------------------------------------------------------------
// Weight converter: three 1024x1024 f32 -> bf16 (grid.y = 3).
__global__ __launch_bounds__(256)
void cvtW_kernel(const float* __restrict__ w0, const float* __restrict__ w1,
                 const float* __restrict__ w2, ushort* __restrict__ d)
{
    const float* s = blockIdx.y == 0 ? w0 : (blockIdx.y == 1 ? w1 : w2);
    ushort* dd = d + (size_t)blockIdx.y * E_ * E_;
    const int idx = (blockIdx.x * 256 + threadIdx.x) * 8;
    f32x4 a = *(const f32x4*)(s + idx);
    f32x4 b = *(const f32x4*)(s + idx + 4);
    *(short8*)(dd + idx) = cvt8(a, b);
}

// ---------------------------------------------------------------------------
// Stage 1: all three projections, one dispatch. grid (128, 8, 3).
// A (f32) staged async into f32 LDS; converted to bf16 at fragment read.
// z=0: Q=(q Wq^T)*s  z=1: K=(k Wk^T)*s  z=2: Vt = (v Wv^T)^T per batch.
__global__ __launch_bounds__(256, 2)
void proj_kernel(const float* __restrict__ q, const float* __restrict__ k,
                 const float* __restrict__ v, const ushort* __restrict__ Wb,
                 ushort* __restrict__ Q, ushort* __restrict__ Kp,
                 ushort* __restrict__ Vt)
{
    __shared__ float  Asf[128 * 32];    // 16 KB
    __shared__ ushort Bs[128 * 32];     //  8 KB
    const int z = blockIdx.z;
    const float* A = (z == 0 ? q : (z == 1 ? k : v)) + (size_t)blockIdx.x * 128 * E_;
    const ushort* W = Wb + (size_t)z * E_ * E_ + (size_t)blockIdx.y * 128 * E_;

    const int tid = threadIdx.x, lane = tid & 63, wave = tid >> 6;
    const int wr = (wave >> 1) * 64, wc = (wave & 1) * 64;
    // A staging: 16 chunks of 1KB = 8 rows x 32 f32; lane -> (row i>>3, col (i&7)*4)
    const int sArow = lane >> 3, sAcol = (lane & 7) * 4;
    // B staging: 8 chunks of 1KB = 16 rows x 32 bf16; lane -> (row i>>2, col (i&3)*8)
    const int sBrow = lane >> 2, sBcol = (lane & 3) * 8;
    const int frow = lane & 15, fk = (lane >> 4) * 8;

    f32x4 acc[4][4];
#pragma unroll
    for (int i = 0; i < 4; ++i)
#pragma unroll
        for (int j = 0; j < 4; ++j) acc[i][j] = (f32x4){0.f, 0.f, 0.f, 0.f};

    for (int ks = 0; ks < E_ / 32; ++ks) {
        const int k0 = ks * 32;
        __syncthreads();
#pragma unroll
        for (int j = 0; j < 4; ++j) {
            const int c = wave * 4 + j;
            async16f(A + (size_t)(c * 8 + sArow) * E_ + k0 + sAcol, Asf + c * 256);
        }
#pragma unroll
        for (int j = 0; j < 2; ++j) {
            const int c = wave * 2 + j;
            async16(W + (size_t)(c * 16 + sBrow) * E_ + k0 + sBcol, Bs + c * 512);
        }
        __syncthreads();

        short8 af[4], bf[4];
#pragma unroll
        for (int i = 0; i < 4; ++i) {
            const float* p = Asf + (wr + i * 16 + frow) * 32 + fk;
            af[i] = cvt8(*(const f32x4*)p, *(const f32x4*)(p + 4));
        }
#pragma unroll
        for (int i = 0; i < 4; ++i)
            bf[i] = *(const short8*)(Bs + (wc + i * 16 + frow) * 32 + fk);
#pragma unroll
        for (int mi = 0; mi < 4; ++mi)
#pragma unroll
            for (int ni = 0; ni < 4; ++ni)
                acc[mi][ni] = __builtin_amdgcn_mfma_f32_16x16x32_bf16(
                    af[mi], bf[ni], acc[mi][ni], 0, 0, 0);
    }

    const float scale = (z == 2) ? 1.0f : 0.17677669529663687f;  // 1/e^(1/4)
    if (z < 2) {
        ushort* D = (z == 0 ? Q : Kp);
#pragma unroll
        for (int mi = 0; mi < 4; ++mi)
#pragma unroll
            for (int r = 0; r < 4; ++r) {
                const int row = blockIdx.x * 128 + wr + mi * 16 + (lane >> 4) * 4 + r;
#pragma unroll
                for (int ni = 0; ni < 4; ++ni) {
                    const int col = blockIdx.y * 128 + wc + ni * 16 + (lane & 15);
                    D[(size_t)row * E_ + col] = f2bf(acc[mi][ni][r] * scale);
                }
            }
    } else {
#pragma unroll
        for (int mi = 0; mi < 4; ++mi)
#pragma unroll
            for (int r = 0; r < 4; ++r) {
                const int rowg = blockIdx.x * 128 + wr + mi * 16 + (lane >> 4) * 4 + r;
                const int bb = rowg >> 11, tl = rowg & 2047;
#pragma unroll
                for (int ni = 0; ni < 4; ++ni) {
                    const int col = blockIdx.y * 128 + wc + ni * 16 + (lane & 15);
                    Vt[(size_t)bb * E_ * T_ + (size_t)col * T_ + tl] = f2bf(acc[mi][ni][r]);
                }
            }
    }
}

// ---------------------------------------------------------------------------
// Stage 2: S = Q K^T causal. Compact lower-triangle grid (136, 8).
__global__ __launch_bounds__(256, 2)
void score_kernel(const ushort* __restrict__ Q, const ushort* __restrict__ K,
                  ushort* __restrict__ S)
{
    __shared__ ushort As[128 * 64];
    __shared__ ushort Bs[128 * 64];
    const int t = blockIdx.x, b = blockIdx.y;
    int br = (int)((sqrtf(8.0f * t + 1.0f) - 1.0f) * 0.5f);
    while ((br + 1) * (br + 2) / 2 <= t) ++br;
    while (br * (br + 1) / 2 > t) --br;
    const int bc = t - br * (br + 1) / 2;

    const ushort* A  = Q + ((size_t)b * T_ + br * 128) * E_;
    const ushort* Bm = K + ((size_t)b * T_ + bc * 128) * E_;

    f32x4 acc[4][4];
#pragma unroll
    for (int i = 0; i < 4; ++i)
#pragma unroll
        for (int j = 0; j < 4; ++j) acc[i][j] = (f32x4){0.f, 0.f, 0.f, 0.f};

    gemm_tile64(A, E_, Bm, E_, E_ / 64, acc, As, Bs);

    const int lane = threadIdx.x & 63, wave = threadIdx.x >> 6;
    const int wr = (wave >> 1) * 64, wc = (wave & 1) * 64;
    ushort* Sb = S + (size_t)b * T_ * T_;
#pragma unroll
    for (int mi = 0; mi < 4; ++mi)
#pragma unroll
        for (int r = 0; r < 4; ++r) {
            const int row = br * 128 + wr + mi * 16 + (lane >> 4) * 4 + r;
#pragma unroll
            for (int ni = 0; ni < 4; ++ni) {
                const int col = bc * 128 + wc + ni * 16 + (lane & 15);
                float val = acc[mi][ni][r];
                if (col > row) val = -1e30f;
                Sb[(size_t)row * T_ + col] = f2bf(val);
            }
        }
}

// ---------------------------------------------------------------------------
// Stage 3: row softmax in place, 16B vector I/O. One block per row.
__global__ __launch_bounds__(256)
void softmax_kernel(ushort* __restrict__ S)
{
    const int gr = blockIdx.x;
    const int b = gr >> 11, i = gr & 2047;
    ushort* row = S + (size_t)b * T_ * T_ + (size_t)i * T_;
    const int Lpad = ((i >> 7) + 1) * 128;
    const int tid = threadIdx.x, lane = tid & 63, wave = tid >> 6;
    __shared__ float red[4];

    const int j0 = tid * 8;
    const bool act = j0 < Lpad;
    float xv[8];
    if (act) {
        int4v dv = *(const int4v*)(row + j0);
        const ushort* u = (const ushort*)&dv;
#pragma unroll
        for (int t = 0; t < 8; ++t) xv[t] = bf2f(u[t]);
    }

    float m = -1e30f;
    if (act)
#pragma unroll
        for (int t = 0; t < 8; ++t) m = fmaxf(m, xv[t]);
#pragma unroll
    for (int o = 32; o; o >>= 1) m = fmaxf(m, __shfl_xor(m, o, 64));
    if (lane == 0) red[wave] = m;
    __syncthreads();
    m = fmaxf(fmaxf(red[0], red[1]), fmaxf(red[2], red[3]));
    __syncthreads();

    float s = 0.f;
    if (act)
#pragma unroll
        for (int t = 0; t < 8; ++t) { xv[t] = __expf(xv[t] - m); s += xv[t]; }
#pragma unroll
    for (int o = 32; o; o >>= 1) s += __shfl_xor(s, o, 64);
    if (lane == 0) red[wave] = s;
    __syncthreads();
    s = red[0] + red[1] + red[2] + red[3];
    const float inv = 1.0f / s;

    if (act) {
        int4v dv;
        ushort* u = (ushort*)&dv;
#pragma unroll
        for (int t = 0; t < 8; ++t) u[t] = f2bf(xv[t] * inv);
        *(int4v*)(row + j0) = dv;
    }
}

// ---------------------------------------------------------------------------
// Stage 4: O = P @ V via V^T (NT, BK=64). grid (8, 16, 8). f32 output.
__global__ __launch_bounds__(256, 2)
void out_kernel(const ushort* __restrict__ P, const ushort* __restrict__ Vt,
                float* __restrict__ O)
{
    __shared__ ushort As[128 * 64];
    __shared__ ushort Bs[128 * 64];
    const int bc = blockIdx.x, br = blockIdx.y, b = blockIdx.z;
    const ushort* A  = P  + (size_t)b * T_ * T_ + (size_t)(br * 128) * T_;
    const ushort* Bm = Vt + (size_t)b * E_ * T_ + (size_t)(bc * 128) * T_;
    const int ksteps = (br + 1) * 2;   // causal K-limit, BK=64

    f32x4 acc[4][4];
#pragma unroll
    for (int i = 0; i < 4; ++i)
#pragma unroll
        for (int j = 0; j < 4; ++j) acc[i][j] = (f32x4){0.f, 0.f, 0.f, 0.f};

    gemm_tile64(A, T_, Bm, T_, ksteps, acc, As, Bs);

    const int lane = threadIdx.x & 63, wave = threadIdx.x >> 6;
    const int wr = (wave >> 1) * 64, wc = (wave & 1) * 64;
    float* Ob = O + (size_t)b * T_ * E_;
#pragma unroll
    for (int mi = 0; mi < 4; ++mi)
#pragma unroll
        for (int r = 0; r < 4; ++r) {
            const int row = br * 128 + wr + mi * 16 + (lane >> 4) * 4 + r;
#pragma unroll
            for (int ni = 0; ni < 4; ++ni) {
                const int col = bc * 128 + wc + ni * 16 + (lane & 15);
                Ob[(size_t)row * E_ + col] = acc[mi][ni][r];
            }
        }
}

// ---------------------------------------------------------------------------
extern "C" void kernel_launch(void* const* d_in, const int* in_sizes, int n_in,
                              void* d_out, int out_size, void* d_ws, size_t ws_size,
                              hipStream_t stream)
{
    const float* q  = (const float*)d_in[0];
    const float* k  = (const float*)d_in[1];
    const float* v  = (const float*)d_in[2];
    const float* Wq = (const float*)d_in[3];
    const float* Wk = (const float*)d_in[4];
    const float* Wv = (const float*)d_in[5];
    float* out = (float*)d_out;

    const size_t nQKV = (size_t)B_ * T_ * E_;      // 16,777,216 elems
    const size_t nW   = (size_t)E_ * E_;
    ushort* Q  = (ushort*)d_ws;
    ushort* K  = Q + nQKV;
    ushort* Vt = K + nQKV;
    ushort* S  = Vt + nQKV;                        // 67 MB
    ushort* Wb = S;                                // weights alias dead S region

    cvtW_kernel<<<dim3(nW / 2048, 3), 256, 0, stream>>>(Wq, Wk, Wv, Wb);
    proj_kernel<<<dim3(128, 8, 3), 256, 0, stream>>>(q, k, v, Wb, Q, K, Vt);
    score_kernel<<<dim3(136, B_), 256, 0, stream>>>(Q, K, S);
    softmax_kernel<<<dim3(B_ * T_), 256, 0, stream>>>(S);
    out_kernel<<<dim3(E_ / 128, T_ / 128, B_), 256, 0, stream>>>(S, Vt, out);
}

// Round 5
// 506.796 us; speedup vs baseline: 1.2986x; 1.0312x over previous
//
#include <hip/hip_runtime.h>
#include <hip/hip_bf16.h>

// ---------------------------------------------------------------------------
// SingleHeadAttention: b=8, t=2048, e=1024. I/O = float32.
//   Q = (q @ Wq^T)/e^0.25 ; K = (k @ Wk^T)/e^0.25 ; V = v @ Wv^T
//   S = Q K^T (causal) ; P = softmax(S) ; O = P V
// bf16 MFMA internals, f32 accumulate, f32 output.
//
// Round-5: XOR-swizzled LDS layouts. global_load_lds forbids padding but the
// per-lane SOURCE address is free, so LDS (row r, granule g) holds global
// (r, g ^ swz(r)); fragment reads apply the same XOR. Kills the 16-way
// bank conflicts (4.4e7 -> ~0) of 128B-row tiles. Packed f32->bf16 cvt.
//  - proj: one dispatch (grid.z=3), f32 A staged directly, BK=32.
//  - score/out: BK=64 (32 MFMA per barrier), compact triangle grid for score.
//  - ws: [Q][K][Vt][S]; bf16 weights alias the dead S region during proj.
// ---------------------------------------------------------------------------

typedef short short8 __attribute__((ext_vector_type(8)));   // 8 x bf16
typedef float f32x4 __attribute__((ext_vector_type(4)));
typedef int   int4v __attribute__((ext_vector_type(4)));

static constexpr int B_ = 8;
static constexpr int T_ = 2048;
static constexpr int E_ = 1024;

__device__ __forceinline__ float bf2f(ushort u) {
    union { unsigned int i; float f; } x; x.i = ((unsigned int)u) << 16; return x.f;
}
__device__ __forceinline__ ushort f2bf(float f) {
    union { float f; unsigned int i; } x; x.f = f;
    unsigned int r = x.i + 0x7fffu + ((x.i >> 16) & 1u);   // RNE
    return (ushort)(r >> 16);
}
// packed f32x8 -> bf16x8 (RNE); compiler emits v_cvt_pk_bf16_f32 when available
__device__ __forceinline__ short8 cvt8(f32x4 a, f32x4 b) {
    short8 r;
    union { __hip_bfloat162 h; unsigned int u; } p;
    unsigned int* ru = (unsigned int*)&r;
    p.h = __float22bfloat162_rn(make_float2(a[0], a[1])); ru[0] = p.u;
    p.h = __float22bfloat162_rn(make_float2(a[2], a[3])); ru[1] = p.u;
    p.h = __float22bfloat162_rn(make_float2(b[0], b[1])); ru[2] = p.u;
    p.h = __float22bfloat162_rn(make_float2(b[2], b[3])); ru[3] = p.u;
    return r;
}

// async 16B global -> LDS; lds base wave-uniform, lane i lands at +16*i.
__device__ __forceinline__ void async16(const ushort* g, ushort* l) {
    __builtin_amdgcn_global_load_lds(
        (const __attribute__((address_space(1))) unsigned int*)g,
        (__attribute__((address_space(3))) unsigned int*)l, 16, 0, 0);
}
__device__ __forceinline__ void async16f(const float* g, float* l) {
    __builtin_amdgcn_global_load_lds(
        (const __attribute__((address_space(1))) unsigned int*)g,
        (__attribute__((address_space(3))) unsigned int*)l, 16, 0, 0);
}

// ---------------------------------------------------------------------------
// BK=64 NT GEMM tile: C[128x128] += A[128xK] * B[128xK]^T, bf16, K contig.
// LDS 128x64 per operand (16 KB). Row = 8 granules of 16B; LDS (r,g) holds
// global (r, g ^ (r&7)) -> conflict-free b128 fragment reads (2-way max).
__device__ __forceinline__ void gemm_tile64(const ushort* __restrict__ A, int lda,
                                            const ushort* __restrict__ Bm, int ldb,
                                            int ksteps, f32x4 (&acc)[4][4],
                                            ushort* As, ushort* Bs)
{
    const int tid = threadIdx.x, lane = tid & 63, wave = tid >> 6;
    const int wr = (wave >> 1) * 64, wc = (wave & 1) * 64;
    const int srow = lane >> 3;                     // row within 8-row chunk
    const int scol = ((lane & 7) ^ srow) * 8;       // swizzled source col (elems)
    const int frow = lane & 15, q4 = lane >> 4;

    for (int ks = 0; ks < ksteps; ++ks) {
        const int k0 = ks * 64;
        __syncthreads();   // prior iter's ds_reads complete before overwrite
#pragma unroll
        for (int j = 0; j < 4; ++j) {
            const int c = wave * 4 + j;             // 16 chunks per operand
            const int grow = c * 8 + srow;
            async16(A  + (size_t)grow * lda + k0 + scol, As + c * 512);
            async16(Bm + (size_t)grow * ldb + k0 + scol, Bs + c * 512);
        }
        __syncthreads();   // drains vmcnt(0)

        short8 af[4][2], bf[4][2];
#pragma unroll
        for (int i = 0; i < 4; ++i) {
            const int ra = wr + i * 16 + frow;
            const int rb = wc + i * 16 + frow;
            const int sw = frow & 7;
#pragma unroll
            for (int kk = 0; kk < 2; ++kk) {
                const int g = (kk * 4 + q4) ^ sw;
                af[i][kk] = *(const short8*)(As + ra * 64 + g * 8);
                bf[i][kk] = *(const short8*)(Bs + rb * 64 + g * 8);
            }
        }
#pragma unroll
        for (int kk = 0; kk < 2; ++kk)
#pragma unroll
            for (int mi = 0; mi < 4; ++mi)
#pragma unroll
                for (int ni = 0; ni < 4; ++ni)
                    acc[mi][ni] = __builtin_amdgcn_mfma_f32_16x16x32_bf16(
                        af[mi][kk], bf[ni][kk], acc[mi][ni], 0, 0, 0);
    }
}

// ---------------------------------------------------------------------------
// Weight converter: three 1024x1024 f32 -> bf16 (grid.y = 3).
__global__ __launch_bounds__(256)
void cvtW_kernel(const float* __restrict__ w0, const float* __restrict__ w1,
                 const float* __restrict__ w2, ushort* __restrict__ d)
{
    const float* s = blockIdx.y == 0 ? w0 : (blockIdx.y == 1 ? w1 : w2);
    ushort* dd = d + (size_t)blockIdx.y * E_ * E_;
    const int idx = (blockIdx.x * 256 + threadIdx.x) * 8;
    f32x4 a = *(const f32x4*)(s + idx);
    f32x4 b = *(const f32x4*)(s + idx + 4);
    *(short8*)(dd + idx) = cvt8(a, b);
}

// ---------------------------------------------------------------------------
// Stage 1: all three projections, one dispatch. grid (128, 8, 3). BK=32.
// A (f32) staged async into swizzled f32 LDS; bf16 at fragment read.
// A tile: 128x32 f32, 8 granules/row, swz = r&7.
// B tile: 128x32 bf16, 4 granules/row, swz = (r>>1)&3 (pairs with r&1 bit).
__global__ __launch_bounds__(256, 2)
void proj_kernel(const float* __restrict__ q, const float* __restrict__ k,
                 const float* __restrict__ v, const ushort* __restrict__ Wb,
                 ushort* __restrict__ Q, ushort* __restrict__ Kp,
                 ushort* __restrict__ Vt)
{
    __shared__ float  Asf[128 * 32];    // 16 KB
    __shared__ ushort Bs[128 * 32];     //  8 KB
    const int z = blockIdx.z;
    const float* A = (z == 0 ? q : (z == 1 ? k : v)) + (size_t)blockIdx.x * 128 * E_;
    const ushort* W = Wb + (size_t)z * E_ * E_ + (size_t)blockIdx.y * 128 * E_;

    const int tid = threadIdx.x, lane = tid & 63, wave = tid >> 6;
    const int wr = (wave >> 1) * 64, wc = (wave & 1) * 64;
    // A staging: chunk = 8 rows x 32 f32; lane -> row lane>>3, src granule ^row
    const int sArow = lane >> 3;
    const int sAcol = ((lane & 7) ^ sArow) * 4;
    // B staging: chunk = 16 rows x 32 bf16; lane -> row lane>>2, src granule ^(row>>1)
    const int sBrow = lane >> 2;
    const int sBcol = ((lane & 3) ^ ((lane >> 3) & 3)) * 8;
    const int frow = lane & 15, q4 = lane >> 4;

    f32x4 acc[4][4];
#pragma unroll
    for (int i = 0; i < 4; ++i)
#pragma unroll
        for (int j = 0; j < 4; ++j) acc[i][j] = (f32x4){0.f, 0.f, 0.f, 0.f};

    for (int ks = 0; ks < E_ / 32; ++ks) {
        const int k0 = ks * 32;
        __syncthreads();
#pragma unroll
        for (int j = 0; j < 4; ++j) {
            const int c = wave * 4 + j;
            async16f(A + (size_t)(c * 8 + sArow) * E_ + k0 + sAcol, Asf + c * 256);
        }
#pragma unroll
        for (int j = 0; j < 2; ++j) {
            const int c = wave * 2 + j;
            async16(W + (size_t)(c * 16 + sBrow) * E_ + k0 + sBcol, Bs + c * 512);
        }
        __syncthreads();

        short8 af[4], bf[4];
#pragma unroll
        for (int i = 0; i < 4; ++i) {
            const int R = wr + i * 16 + frow;
            const int g0 = (q4 * 2) ^ (frow & 7);
            const int g1 = g0 ^ 1;
            f32x4 lo = *(const f32x4*)(Asf + R * 32 + g0 * 4);
            f32x4 hi = *(const f32x4*)(Asf + R * 32 + g1 * 4);
            af[i] = cvt8(lo, hi);
        }
#pragma unroll
        for (int i = 0; i < 4; ++i) {
            const int R = wc + i * 16 + frow;
            const int g = q4 ^ ((frow >> 1) & 3);
            bf[i] = *(const short8*)(Bs + R * 32 + g * 8);
        }
#pragma unroll
        for (int mi = 0; mi < 4; ++mi)
#pragma unroll
            for (int ni = 0; ni < 4; ++ni)
                acc[mi][ni] = __builtin_amdgcn_mfma_f32_16x16x32_bf16(
                    af[mi], bf[ni], acc[mi][ni], 0, 0, 0);
    }

    const float scale = (z == 2) ? 1.0f : 0.17677669529663687f;  // 1/e^(1/4)
    if (z < 2) {
        ushort* D = (z == 0 ? Q : Kp);
#pragma unroll
        for (int mi = 0; mi < 4; ++mi)
#pragma unroll
            for (int r = 0; r < 4; ++r) {
                const int row = blockIdx.x * 128 + wr + mi * 16 + (lane >> 4) * 4 + r;
#pragma unroll
                for (int ni = 0; ni < 4; ++ni) {
                    const int col = blockIdx.y * 128 + wc + ni * 16 + (lane & 15);
                    D[(size_t)row * E_ + col] = f2bf(acc[mi][ni][r] * scale);
                }
            }
    } else {
#pragma unroll
        for (int mi = 0; mi < 4; ++mi)
#pragma unroll
            for (int r = 0; r < 4; ++r) {
                const int rowg = blockIdx.x * 128 + wr + mi * 16 + (lane >> 4) * 4 + r;
                const int bb = rowg >> 11, tl = rowg & 2047;
#pragma unroll
                for (int ni = 0; ni < 4; ++ni) {
                    const int col = blockIdx.y * 128 + wc + ni * 16 + (lane & 15);
                    Vt[(size_t)bb * E_ * T_ + (size_t)col * T_ + tl] = f2bf(acc[mi][ni][r]);
                }
            }
    }
}

// ---------------------------------------------------------------------------
// Stage 2: S = Q K^T causal. Compact lower-triangle grid (136, 8).
__global__ __launch_bounds__(256, 2)
void score_kernel(const ushort* __restrict__ Q, const ushort* __restrict__ K,
                  ushort* __restrict__ S)
{
    __shared__ ushort As[128 * 64];
    __shared__ ushort Bs[128 * 64];
    const int t = blockIdx.x, b = blockIdx.y;
    int br = (int)((sqrtf(8.0f * t + 1.0f) - 1.0f) * 0.5f);
    while ((br + 1) * (br + 2) / 2 <= t) ++br;
    while (br * (br + 1) / 2 > t) --br;
    const int bc = t - br * (br + 1) / 2;

    const ushort* A  = Q + ((size_t)b * T_ + br * 128) * E_;
    const ushort* Bm = K + ((size_t)b * T_ + bc * 128) * E_;

    f32x4 acc[4][4];
#pragma unroll
    for (int i = 0; i < 4; ++i)
#pragma unroll
        for (int j = 0; j < 4; ++j) acc[i][j] = (f32x4){0.f, 0.f, 0.f, 0.f};

    gemm_tile64(A, E_, Bm, E_, E_ / 64, acc, As, Bs);

    const int lane = threadIdx.x & 63, wave = threadIdx.x >> 6;
    const int wr = (wave >> 1) * 64, wc = (wave & 1) * 64;
    ushort* Sb = S + (size_t)b * T_ * T_;
#pragma unroll
    for (int mi = 0; mi < 4; ++mi)
#pragma unroll
        for (int r = 0; r < 4; ++r) {
            const int row = br * 128 + wr + mi * 16 + (lane >> 4) * 4 + r;
#pragma unroll
            for (int ni = 0; ni < 4; ++ni) {
                const int col = bc * 128 + wc + ni * 16 + (lane & 15);
                float val = acc[mi][ni][r];
                if (col > row) val = -1e30f;
                Sb[(size_t)row * T_ + col] = f2bf(val);
            }
        }
}

// ---------------------------------------------------------------------------
// Stage 3: row softmax in place, 16B vector I/O. One block per row.
__global__ __launch_bounds__(256)
void softmax_kernel(ushort* __restrict__ S)
{
    const int gr = blockIdx.x;
    const int b = gr >> 11, i = gr & 2047;
    ushort* row = S + (size_t)b * T_ * T_ + (size_t)i * T_;
    const int Lpad = ((i >> 7) + 1) * 128;
    const int tid = threadIdx.x, lane = tid & 63, wave = tid >> 6;
    __shared__ float red[4];

    const int j0 = tid * 8;
    const bool act = j0 < Lpad;
    float xv[8];
    if (act) {
        int4v dv = *(const int4v*)(row + j0);
        const ushort* u = (const ushort*)&dv;
#pragma unroll
        for (int t = 0; t < 8; ++t) xv[t] = bf2f(u[t]);
    }

    float m = -1e30f;
    if (act)
#pragma unroll
        for (int t = 0; t < 8; ++t) m = fmaxf(m, xv[t]);
#pragma unroll
    for (int o = 32; o; o >>= 1) m = fmaxf(m, __shfl_xor(m, o, 64));
    if (lane == 0) red[wave] = m;
    __syncthreads();
    m = fmaxf(fmaxf(red[0], red[1]), fmaxf(red[2], red[3]));
    __syncthreads();

    float s = 0.f;
    if (act)
#pragma unroll
        for (int t = 0; t < 8; ++t) { xv[t] = __expf(xv[t] - m); s += xv[t]; }
#pragma unroll
    for (int o = 32; o; o >>= 1) s += __shfl_xor(s, o, 64);
    if (lane == 0) red[wave] = s;
    __syncthreads();
    s = red[0] + red[1] + red[2] + red[3];
    const float inv = 1.0f / s;

    if (act) {
        int4v dv;
        ushort* u = (ushort*)&dv;
#pragma unroll
        for (int t = 0; t < 8; ++t) u[t] = f2bf(xv[t] * inv);
        *(int4v*)(row + j0) = dv;
    }
}

// ---------------------------------------------------------------------------
// Stage 4: O = P @ V via V^T (NT, BK=64). grid (8, 16, 8). f32 output.
__global__ __launch_bounds__(256, 2)
void out_kernel(const ushort* __restrict__ P, const ushort* __restrict__ Vt,
                float* __restrict__ O)
{
    __shared__ ushort As[128 * 64];
    __shared__ ushort Bs[128 * 64];
    const int bc = blockIdx.x, br = blockIdx.y, b = blockIdx.z;
    const ushort* A  = P  + (size_t)b * T_ * T_ + (size_t)(br * 128) * T_;
    const ushort* Bm = Vt + (size_t)b * E_ * T_ + (size_t)(bc * 128) * T_;
    const int ksteps = (br + 1) * 2;   // causal K-limit, BK=64

    f32x4 acc[4][4];
#pragma unroll
    for (int i = 0; i < 4; ++i)
#pragma unroll
        for (int j = 0; j < 4; ++j) acc[i][j] = (f32x4){0.f, 0.f, 0.f, 0.f};

    gemm_tile64(A, T_, Bm, T_, ksteps, acc, As, Bs);

    const int lane = threadIdx.x & 63, wave = threadIdx.x >> 6;
    const int wr = (wave >> 1) * 64, wc = (wave & 1) * 64;
    float* Ob = O + (size_t)b * T_ * E_;
#pragma unroll
    for (int mi = 0; mi < 4; ++mi)
#pragma unroll
        for (int r = 0; r < 4; ++r) {
            const int row = br * 128 + wr + mi * 16 + (lane >> 4) * 4 + r;
#pragma unroll
            for (int ni = 0; ni < 4; ++ni) {
                const int col = bc * 128 + wc + ni * 16 + (lane & 15);
                Ob[(size_t)row * E_ + col] = acc[mi][ni][r];
            }
        }
}

// ---------------------------------------------------------------------------
extern "C" void kernel_launch(void* const* d_in, const int* in_sizes, int n_in,
                              void* d_out, int out_size, void* d_ws, size_t ws_size,
                              hipStream_t stream)
{
    const float* q  = (const float*)d_in[0];
    const float* k  = (const float*)d_in[1];
    const float* v  = (const float*)d_in[2];
    const float* Wq = (const float*)d_in[3];
    const float* Wk = (const float*)d_in[4];
    const float* Wv = (const float*)d_in[5];
    float* out = (float*)d_out;

    const size_t nQKV = (size_t)B_ * T_ * E_;      // 16,777,216 elems
    const size_t nW   = (size_t)E_ * E_;
    ushort* Q  = (ushort*)d_ws;
    ushort* K  = Q + nQKV;
    ushort* Vt = K + nQKV;
    ushort* S  = Vt + nQKV;                        // 67 MB
    ushort* Wb = S;                                // weights alias dead S region

    cvtW_kernel<<<dim3(nW / 2048, 3), 256, 0, stream>>>(Wq, Wk, Wv, Wb);
    proj_kernel<<<dim3(128, 8, 3), 256, 0, stream>>>(q, k, v, Wb, Q, K, Vt);
    score_kernel<<<dim3(136, B_), 256, 0, stream>>>(Q, K, S);
    softmax_kernel<<<dim3(B_ * T_), 256, 0, stream>>>(S);
    out_kernel<<<dim3(E_ / 128, T_ / 128, B_), 256, 0, stream>>>(S, Vt, out);
}